// Round 3
// baseline (190.935 us; speedup 1.0000x reference)
//
#include <hip/hip_runtime.h>
#include <cmath>

#define HH 512
#define WW 512
#define TW 32
#define TH 64
#define INH 74          /* TH + 10 halo rows */
#define HPS 36          /* hp row stride in dwords (mult of 4) */
#define NTHREADS 512    /* 8 waves; LDS 43.0 KB -> 3 blocks/CU with wide margin */
#define C1F 0.0001f
#define C2F 0.0009f

struct GaussW { float w[11]; };

// 4-field sum/diff reformulation: a=p+t, b=p-t.
//   A=G*a=mu1+mu2, B=G*b=mu1-mu2, EA=G*(a^2), EB=G*(b^2)
//   mu1^2+mu2^2=(A^2+B^2)/2, mu1*mu2=(A^2-B^2)/4,
//   e11+e22=(EA+EB)/2, e12=(EA-EB)/4
// -> 4 convolved fields instead of 5: -20% LDS bytes/FMAs in phase C,
//    LDS block 53760->43008 B so 3 blocks/CU fits with ~35KB slack
//    (at 53.8KB, 3x left only 2.5KB slack -> suspected 2-block residency).
__global__ __launch_bounds__(NTHREADS) void ssim_tile_kernel(
    const float* __restrict__ pred, const float* __restrict__ targ,
    float* __restrict__ partial, GaussW gw)
{
    __shared__ __align__(16) float hp[4][INH][HPS];
    __shared__ float wred[8];

    const int tid = threadIdx.x;
    const int bx = blockIdx.x, by = blockIdx.y, bz = blockIdx.z;
    const int gx0 = bx * TW;
    const int gy0 = by * TH - 5;
    const size_t plane = (size_t)bz * (size_t)(HH * WW);

    const bool xinterior = (bx > 0) && (bx < (WW / TW) - 1);

    // ---- Phase B: horizontal Gaussian on (a,b,a^2,b^2) from global ----
    // 592 tasks: 74 rows x 8 col-groups, each computes 4 output cols.
    if (xinterior) {
        for (int i = tid; i < INH * 8; i += NTHREADS) {
            int r = i >> 3;
            int c0 = (i & 7) << 2;
            int gr = gy0 + r;
            // p[m]/t[m] hold input col c0-6+m, m=0..15 (need m=1..14)
            float p[16], t[16];
            if ((unsigned)gr < (unsigned)HH) {
                const float* prow = pred + plane + (size_t)gr * WW + (gx0 + c0 - 6);
                const float* trow = targ + plane + (size_t)gr * WW + (gx0 + c0 - 6);
                *(float2*)&p[0]  = *(const float2*)(prow);
                *(float4*)&p[2]  = *(const float4*)(prow + 2);
                *(float4*)&p[6]  = *(const float4*)(prow + 6);
                *(float4*)&p[10] = *(const float4*)(prow + 10);
                *(float2*)&p[14] = *(const float2*)(prow + 14);
                *(float2*)&t[0]  = *(const float2*)(trow);
                *(float4*)&t[2]  = *(const float4*)(trow + 2);
                *(float4*)&t[6]  = *(const float4*)(trow + 6);
                *(float4*)&t[10] = *(const float4*)(trow + 10);
                *(float2*)&t[14] = *(const float2*)(trow + 14);
            } else {
                #pragma unroll
                for (int m = 0; m < 16; m++) { p[m] = 0.f; t[m] = 0.f; }
            }

            // in-place butterfly: p[m] <- a = p+t, t[m] <- b = p-t
            #pragma unroll
            for (int m = 1; m < 15; m++) {
                float pv = p[m], tv = t[m];
                p[m] = pv + tv;
                t[m] = pv - tv;
            }

            float sa[4]  = {0,0,0,0}, sb[4]  = {0,0,0,0};
            float saa[4] = {0,0,0,0}, sbb[4] = {0,0,0,0};
            #pragma unroll
            for (int k = 0; k < 11; k++) {
                float wk = gw.w[k];
                #pragma unroll
                for (int o = 0; o < 4; o++) {
                    float av = p[o + k + 1], bv = t[o + k + 1];
                    float wa = wk * av, wb = wk * bv;
                    sa[o]  += wa;
                    sb[o]  += wb;
                    saa[o] += wa * av;
                    sbb[o] += wb * bv;
                }
            }
            *(float4*)&hp[0][r][c0] = make_float4(sa[0],  sa[1],  sa[2],  sa[3]);
            *(float4*)&hp[1][r][c0] = make_float4(sb[0],  sb[1],  sb[2],  sb[3]);
            *(float4*)&hp[2][r][c0] = make_float4(saa[0], saa[1], saa[2], saa[3]);
            *(float4*)&hp[3][r][c0] = make_float4(sbb[0], sbb[1], sbb[2], sbb[3]);
        }
    } else {
        for (int i = tid; i < INH * 8; i += NTHREADS) {
            int r = i >> 3;
            int c0 = (i & 7) << 2;
            int gr = gy0 + r;
            float p[14], t[14];
            if ((unsigned)gr < (unsigned)HH) {
                const size_t rb = plane + (size_t)gr * WW;
                int cbase = gx0 + c0 - 5;
                #pragma unroll
                for (int m = 0; m < 14; m++) {
                    int gc = cbase + m;
                    int cc = min(max(gc, 0), WW - 1);
                    bool in = (unsigned)gc < (unsigned)WW;
                    float pv = pred[rb + cc];
                    float tv = targ[rb + cc];
                    p[m] = in ? pv : 0.f;
                    t[m] = in ? tv : 0.f;
                }
            } else {
                #pragma unroll
                for (int m = 0; m < 14; m++) { p[m] = 0.f; t[m] = 0.f; }
            }

            #pragma unroll
            for (int m = 0; m < 14; m++) {
                float pv = p[m], tv = t[m];
                p[m] = pv + tv;
                t[m] = pv - tv;
            }

            float sa[4]  = {0,0,0,0}, sb[4]  = {0,0,0,0};
            float saa[4] = {0,0,0,0}, sbb[4] = {0,0,0,0};
            #pragma unroll
            for (int k = 0; k < 11; k++) {
                float wk = gw.w[k];
                #pragma unroll
                for (int o = 0; o < 4; o++) {
                    float av = p[o + k], bv = t[o + k];
                    float wa = wk * av, wb = wk * bv;
                    sa[o]  += wa;
                    sb[o]  += wb;
                    saa[o] += wa * av;
                    sbb[o] += wb * bv;
                }
            }
            *(float4*)&hp[0][r][c0] = make_float4(sa[0],  sa[1],  sa[2],  sa[3]);
            *(float4*)&hp[1][r][c0] = make_float4(sb[0],  sb[1],  sb[2],  sb[3]);
            *(float4*)&hp[2][r][c0] = make_float4(saa[0], saa[1], saa[2], saa[3]);
            *(float4*)&hp[3][r][c0] = make_float4(sbb[0], sbb[1], sbb[2], sbb[3]);
        }
    }
    __syncthreads();

    // ---- Phase C: vertical Gaussian, 4 rows x 1 col per thread + SSIM ----
    // 512 threads x 4 outputs = 2048 = 32x64 tile. Conflict-free b32 reads
    // (bank = (4r + c) mod 32, all 32 cols distinct; 2 lanes/bank is free).
    float local = 0.f;
    {
        const int c0 = tid & 31;            // 0..31
        const int r0 = (tid >> 5) << 2;     // 0..60
        const float* hbase = &hp[0][r0][c0];

        float acc[4][4];
        #pragma unroll
        for (int f = 0; f < 4; f++)
            #pragma unroll
            for (int rr = 0; rr < 4; rr++)
                acc[f][rr] = 0.f;

        #pragma unroll
        for (int jj = 0; jj < 14; jj++) {
            float v[4];
            #pragma unroll
            for (int f = 0; f < 4; f++)
                v[f] = hbase[f * (INH * HPS) + jj * HPS];
            #pragma unroll
            for (int rr = 0; rr < 4; rr++) {
                int k = jj - rr;
                if (k >= 0 && k < 11) {
                    float wk = gw.w[k];
                    #pragma unroll
                    for (int f = 0; f < 4; f++)
                        acc[f][rr] += wk * v[f];
                }
            }
        }

        #pragma unroll
        for (int rr = 0; rr < 4; rr++) {
            float A  = acc[0][rr], Bv = acc[1][rr];
            float EA = acc[2][rr], EB = acc[3][rr];
            float A2 = A * A, B2 = Bv * Bv;
            float S  = 0.5f  * (A2 + B2);      // mu1^2 + mu2^2
            float P  = 0.25f * (A2 - B2);      // mu1 * mu2
            float Ep = 0.5f  * (EA + EB);      // e11 + e22
            float Ec = 0.25f * (EA - EB);      // e12
            float num = (2.f * P + C1F) * (2.f * (Ec - P) + C2F);
            float den = (S + C1F) * ((Ep - S) + C2F);
            local += num * __builtin_amdgcn_rcpf(den);
        }
    }

    // ---- block reduction (8 waves) ----
    #pragma unroll
    for (int off = 32; off > 0; off >>= 1)
        local += __shfl_down(local, off, 64);
    int lane = tid & 63, wid = tid >> 6;
    if (lane == 0) wred[wid] = local;
    __syncthreads();
    if (tid == 0) {
        float s = 0.f;
        #pragma unroll
        for (int w2 = 0; w2 < 8; w2++) s += wred[w2];
        int bid = (bz * gridDim.y + by) * gridDim.x + bx;
        partial[bid] = s;
    }
}

__global__ __launch_bounds__(256) void ssim_finalize_kernel(
    const float* __restrict__ partial, int n, float inv_count,
    float* __restrict__ out)
{
    __shared__ float sm[4];
    float s = 0.f;
    for (int i = threadIdx.x; i < n; i += 256)
        s += partial[i];
    #pragma unroll
    for (int off = 32; off > 0; off >>= 1)
        s += __shfl_down(s, off, 64);
    int lane = threadIdx.x & 63, wid = threadIdx.x >> 6;
    if (lane == 0) sm[wid] = s;
    __syncthreads();
    if (threadIdx.x == 0)
        out[0] = 1.0f - (sm[0] + sm[1] + sm[2] + sm[3]) * inv_count;
}

extern "C" void kernel_launch(void* const* d_in, const int* in_sizes, int n_in,
                              void* d_out, int out_size, void* d_ws, size_t ws_size,
                              hipStream_t stream)
{
    const float* pred = (const float*)d_in[0];
    const float* targ = (const float*)d_in[1];
    float* out = (float*)d_out;
    float* partial = (float*)d_ws;

    const int total = in_sizes[0];                 // 16*3*512*512 = 12582912
    const int nplanes = total / (HH * WW);         // 48

    GaussW gw;
    double g[11], s = 0.0;
    for (int i = 0; i < 11; i++) {
        double d = (double)(i - 5);
        g[i] = exp(-d * d / 4.5);
        s += g[i];
    }
    for (int i = 0; i < 11; i++) gw.w[i] = (float)(g[i] / s);

    dim3 grid(WW / TW, HH / TH, nplanes);          // 16 x 8 x 48 = 6144 blocks
    ssim_tile_kernel<<<grid, NTHREADS, 0, stream>>>(pred, targ, partial, gw);

    const int nblocks = (WW / TW) * (HH / TH) * nplanes;
    const float inv_count = 1.0f / (float)total;
    ssim_finalize_kernel<<<1, 256, 0, stream>>>(partial, nblocks, inv_count, out);
}